// Round 1
// baseline (192.644 us; speedup 1.0000x reference)
//
#include <hip/hip_runtime.h>

#define NM 23        // 3*K - 1, K = 8
#define D_DIM 64
#define H1_DIM 64
#define H2_DIM 32
#define ROWS 64

// ---------------------------------------------------------------------------
// Prep: apply MADE masks + transpose weights into workspace.
//   W1t[d][i]    = W1[i][d] * m1[i][d]          (4096 floats)
//   W2t[i][j]    = W2[j][i] * m2[j][i]          (2048 floats)
//   W3t[d][m][k] = W3[m*64+d][k] * m3[...][k]   (47104 floats)
//   b3t[d][m]    = b3[m*64+d]                   (1472 floats)
// ---------------------------------------------------------------------------
__global__ __launch_bounds__(256) void prep_kernel(
    const float* __restrict__ W1, const float* __restrict__ W2,
    const float* __restrict__ W3, const float* __restrict__ b3,
    float* __restrict__ W1t, float* __restrict__ W2t,
    float* __restrict__ W3t, float* __restrict__ b3t) {
  int idx = blockIdx.x * 256 + threadIdx.x;
  if (idx < H1_DIM * D_DIM) {                 // W1t[d][i]
    int d = idx >> 6, i = idx & 63;
    int deg = (i % 63) + 1;                   // h1deg[i]
    W1t[idx] = (d < deg) ? W1[i * D_DIM + d] : 0.f;
  }
  if (idx < H1_DIM * H2_DIM) {                // W2t[i][j]
    int i = idx >> 5, j = idx & 31;
    int hdeg = (i % 63) + 1;
    W2t[idx] = (hdeg <= j + 1) ? W2[j * H1_DIM + i] : 0.f;
  }
  if (idx < D_DIM * NM * H2_DIM) {            // W3t[d][m][k]
    int d = idx / (NM * H2_DIM);
    int rem = idx - d * (NM * H2_DIM);
    int m = rem >> 5, k = rem & 31;
    W3t[idx] = (k < d) ? W3[(m * D_DIM + d) * H2_DIM + k] : 0.f;
  }
  if (idx < D_DIM * NM) {                     // b3t[d][m]
    int d = idx / NM, m = idx - d * NM;
    b3t[idx] = b3[m * D_DIM + d];
  }
}

__device__ __forceinline__ float softplus_f(float v) {
  // stable: max(v,0) + log(1 + exp(-|v|))
  return fmaxf(v, 0.f) + __logf(1.f + __expf(-fabsf(v)));
}

// ---------------------------------------------------------------------------
// Main fused kernel: 64 rows per block, 256 threads (4 waves), lane = row.
// All weight indices are wave-uniform -> scalar loads.
// ---------------------------------------------------------------------------
__global__ __launch_bounds__(256) void spline_kernel(
    const float* __restrict__ x,
    const float* __restrict__ W1t, const float* __restrict__ b1,
    const float* __restrict__ W2t, const float* __restrict__ b2,
    const float* __restrict__ W3t, const float* __restrict__ b3t,
    float* __restrict__ out, int B) {
  __shared__ float xs[ROWS][D_DIM + 1];    // +1 pad: 2-way bank alias (free)
  __shared__ float h1s[ROWS][H1_DIM + 1];  // reused as z-staging later
  __shared__ float h2s[ROWS][H2_DIM + 1];
  __shared__ float ldp[4][ROWS];

  const int t = threadIdx.x;
  const int b0 = blockIdx.x * ROWS;

  // ---- stage x tile (coalesced float4) ----
  for (int q = t; q < ROWS * 16; q += 256) {
    int rr = q >> 4;
    int c4 = (q & 15) * 4;
    const float4 v =
        *reinterpret_cast<const float4*>(x + (size_t)b0 * D_DIM + (size_t)q * 4);
    xs[rr][c4 + 0] = v.x; xs[rr][c4 + 1] = v.y;
    xs[rr][c4 + 2] = v.z; xs[rr][c4 + 3] = v.w;
  }
  __syncthreads();

  const int r  = t & 63;    // lane = row
  const int wv = t >> 6;    // wave id 0..3

  // ---- layer 1: h1[r][i] for i in [wv*16, wv*16+16) ----
  const int iBase = __builtin_amdgcn_readfirstlane(wv * 16);
  float acc1[16];
  #pragma unroll
  for (int ii = 0; ii < 16; ++ii) acc1[ii] = b1[iBase + ii];
  #pragma unroll 4
  for (int dd = 0; dd < 64; ++dd) {
    float xv = xs[r][dd];
    const float* wrow = W1t + dd * 64 + iBase;
    #pragma unroll
    for (int ii = 0; ii < 16; ++ii) acc1[ii] = fmaf(xv, wrow[ii], acc1[ii]);
  }
  #pragma unroll
  for (int ii = 0; ii < 16; ++ii) h1s[r][iBase + ii] = fmaxf(acc1[ii], 0.f);
  __syncthreads();

  // ---- layer 2: h2[r][j] for j in [wv*8, wv*8+8) ----
  const int jBase = __builtin_amdgcn_readfirstlane(wv * 8);
  float acc2[8];
  #pragma unroll
  for (int jj = 0; jj < 8; ++jj) acc2[jj] = b2[jBase + jj];
  #pragma unroll 4
  for (int i2 = 0; i2 < 64; ++i2) {
    float hv = h1s[r][i2];
    const float* wrow = W2t + i2 * 32 + jBase;
    #pragma unroll
    for (int jj = 0; jj < 8; ++jj) acc2[jj] = fmaf(hv, wrow[jj], acc2[jj]);
  }
  #pragma unroll
  for (int jj = 0; jj < 8; ++jj) h2s[r][jBase + jj] = fmaxf(acc2[jj], 0.f);
  __syncthreads();

  // ---- h2 row into registers ----
  float h2r[32];
  #pragma unroll
  for (int k = 0; k < 32; ++k) h2r[k] = h2s[r][k];

  float ldacc = 0.f;

  // ---- layer 3 + spline, 16 d-values per thread ----
  #pragma unroll 1
  for (int di = 0; di < 16; ++di) {
    const int dU = __builtin_amdgcn_readfirstlane(wv * 16 + di);
    const float* w3d = W3t + dU * (NM * 32);
    const float* b3d = b3t + dU * NM;

    float p[NM];
    #pragma unroll
    for (int m = 0; m < NM; ++m) {
      float acc = b3d[m];
      const float* wrow = w3d + m * 32;
      #pragma unroll
      for (int k = 0; k < 32; ++k) acc = fmaf(h2r[k], wrow[k], acc);
      p[m] = acc;
    }

    const float xv = xs[r][dU];
    const float xc = fminf(fmaxf(xv, -3.f), 3.f);

    // softmax over widths logits p[0..7]
    float mw = p[0];
    #pragma unroll
    for (int k = 1; k < 8; ++k) mw = fmaxf(mw, p[k]);
    float ew[8], sw = 0.f;
    #pragma unroll
    for (int k = 0; k < 8; ++k) { ew[k] = __expf(p[k] - mw); sw += ew[k]; }
    const float invw = 1.f / sw;

    // softmax over heights logits p[8..15]
    float mh = p[8];
    #pragma unroll
    for (int k = 1; k < 8; ++k) mh = fmaxf(mh, p[8 + k]);
    float eh[8], sh = 0.f;
    #pragma unroll
    for (int k = 0; k < 8; ++k) { eh[k] = __expf(p[8 + k] - mh); sh += eh[k]; }
    const float invh = 1.f / sh;

    const float WSC = 1.0f - 1e-3f * 8.0f;   // 1 - MIN_BIN_WIDTH*K
    float cumw[9], cumh[9];
    cumw[0] = -3.f; cumh[0] = -3.f;
    float cw = 0.f, ch = 0.f;
    #pragma unroll
    for (int k = 0; k < 7; ++k) {
      cw += 1e-3f + WSC * (ew[k] * invw);
      ch += 1e-3f + WSC * (eh[k] * invh);
      cumw[k + 1] = fmaf(6.f, cw, -3.f);
      cumh[k + 1] = fmaf(6.f, ch, -3.f);
    }
    cumw[8] = 3.f; cumh[8] = 3.f;

    float derivs[9];
    derivs[0] = 1.f; derivs[8] = 1.f;
    #pragma unroll
    for (int k = 0; k < 7; ++k) derivs[k + 1] = 1e-3f + softplus_f(p[16 + k]);

    // bin select: idx = sum(xc >= cumw[k]+EPS) - 1, clipped to [0,7]
    float xk = cumw[0], xk1 = cumw[1];
    float yk = cumh[0], yk1 = cumh[1];
    float dk = derivs[0], dk1 = derivs[1];
    #pragma unroll
    for (int k = 1; k < 8; ++k) {
      bool s = xc >= cumw[k] + 1e-6f;
      xk  = s ? cumw[k]     : xk;
      xk1 = s ? cumw[k + 1] : xk1;
      yk  = s ? cumh[k]     : yk;
      yk1 = s ? cumh[k + 1] : yk1;
      dk  = s ? derivs[k]   : dk;
      dk1 = s ? derivs[k + 1] : dk1;
    }

    const float wk = xk1 - xk, hk = yk1 - yk;
    const float invwk = 1.f / wk;
    const float delta = hk * invwk;
    const float theta = (xc - xk) * invwk;
    const float omt = 1.f - theta;
    const float tt = theta * omt;
    const float th2 = theta * theta;
    const float num = hk * (delta * th2 + dk * tt);
    const float den = delta + (dk + dk1 - 2.f * delta) * tt;
    const float yv = yk + num / den;
    const float dnum = delta * delta * (dk1 * th2 + 2.f * delta * tt + dk * omt * omt);
    const float ldv = __logf(dnum) - 2.f * __logf(den);

    const bool inside = (xv >= -3.f) && (xv <= 3.f);
    h1s[r][dU] = inside ? yv : xv;           // z staging (h1s free after layer2)
    ldacc += inside ? ldv : 0.f;
  }

  ldp[wv][r] = ldacc;
  __syncthreads();

  // ---- coalesced z write ----
  for (int q = t; q < ROWS * 16; q += 256) {
    int rr = q >> 4;
    int c4 = (q & 15) * 4;
    float4 v = make_float4(h1s[rr][c4 + 0], h1s[rr][c4 + 1],
                           h1s[rr][c4 + 2], h1s[rr][c4 + 3]);
    *reinterpret_cast<float4*>(out + (size_t)b0 * D_DIM + (size_t)q * 4) = v;
  }
  // ---- log-det sum output ----
  if (t < 64) {
    float s = ldp[0][t] + ldp[1][t] + ldp[2][t] + ldp[3][t];
    out[(size_t)B * D_DIM + b0 + t] = s;
  }
}

extern "C" void kernel_launch(void* const* d_in, const int* in_sizes, int n_in,
                              void* d_out, int out_size, void* d_ws, size_t ws_size,
                              hipStream_t stream) {
  const float* x  = (const float*)d_in[0];
  const float* W1 = (const float*)d_in[1];
  const float* b1 = (const float*)d_in[2];
  const float* W2 = (const float*)d_in[3];
  const float* b2 = (const float*)d_in[4];
  const float* W3 = (const float*)d_in[5];
  const float* b3 = (const float*)d_in[6];
  float* out = (float*)d_out;
  float* ws  = (float*)d_ws;

  float* W1t = ws;                       // 4096
  float* W2t = ws + 4096;                // 2048
  float* W3t = ws + 6144;                // 47104
  float* b3t = ws + 53248;               // 1472

  const int B = in_sizes[0] / D_DIM;     // 32768

  const int prep_elems = D_DIM * NM * H2_DIM;            // 47104 (largest)
  prep_kernel<<<(prep_elems + 255) / 256, 256, 0, stream>>>(
      W1, W2, W3, b3, W1t, W2t, W3t, b3t);

  spline_kernel<<<B / ROWS, 256, 0, stream>>>(
      x, W1t, b1, W2t, b2, W3t, b3t, out, B);
}